// Round 6
// baseline (1595.820 us; speedup 1.0000x reference)
//
#include <hip/hip_runtime.h>
#include <hip/hip_bf16.h>
#include <math.h>

#define N_NODES 100000
#define N_EDGES 1600000
#define NEG_SLOPE 0.2f

// bucket = dst >> 7 : 128 nodes per bucket
#define NB_BUCKET 782

// ---- workspace layout (bytes) ----
#define OFF_H     0              // N*128 bf16 = 25,600,000
#define OFF_ASRC  25600000       // N*4 f32
#define OFF_ADST  27200000       // N*4 f32
#define OFF_BCNT  28800000       // 782 int (pad 4096)
#define OFF_BOFF  28804096       // 783 int (pad 4096)
#define OFF_BCUR  28808192       // 782 int (pad 4096)
#define OFF_WHI   28812288       // 32768
#define OFF_WLO   28845056       // 32768
#define OFF_TMP   28877824       // E uint = 6,400,000
// total ≈ 35.3 MB

typedef short short8 __attribute__((ext_vector_type(8)));
typedef float floatx4 __attribute__((ext_vector_type(4)));

__device__ __forceinline__ float leaky(float x) {
    return fmaxf(x, NEG_SLOPE * x);
}
__device__ __forceinline__ float bf_lo(unsigned int u) {
    return __uint_as_float(u << 16);
}
__device__ __forceinline__ float bf_hi(unsigned int u) {
    return __uint_as_float(u & 0xffff0000u);
}
__device__ __forceinline__ unsigned int pack_bf2(float a, float b) {
    unsigned int ua = (unsigned int)__bfloat16_as_ushort(__float2bfloat16(a));
    unsigned int ub = (unsigned int)__bfloat16_as_ushort(__float2bfloat16(b));
    return ua | (ub << 16);
}
// split a pair of fp32 into packed bf16 hi (truncated) and bf16 lo (residual)
__device__ __forceinline__ void split_pack(float a0, float a1,
                                           unsigned int& hi, unsigned int& lo) {
    const unsigned int u0 = __float_as_uint(a0);
    const unsigned int u1 = __float_as_uint(a1);
    hi = (u0 >> 16) | (u1 & 0xffff0000u);
    const float l0 = a0 - __uint_as_float(u0 & 0xffff0000u);
    const float l1 = a1 - __uint_as_float(u1 & 0xffff0000u);
    lo = (__float_as_uint(l0) >> 16) | (__float_as_uint(l1) & 0xffff0000u);
}

// ---------------------------------------------------------------------------
// K0: W -> MFMA B-fragment order, bf16 hi/lo (proven R5 layout)
// ---------------------------------------------------------------------------
__global__ __launch_bounds__(256) void wfrag_kernel(
    const float* __restrict__ W, uint4* __restrict__ whi, uint4* __restrict__ wlo)
{
    const int t    = blockIdx.x * 256 + threadIdx.x;
    const int lane = t & 63;
    const int nt   = (t >> 6) & 7;
    const int kt   = t >> 9;
    const int c    = lane & 15;
    const int quad = lane >> 4;
    const int n    = nt * 16 + c;
    const int k0   = kt * 32 + quad * 8;

    unsigned int hu[4], lu[4];
#pragma unroll
    for (int j = 0; j < 4; ++j) {
        const float a0 = W[(size_t)(k0 + 2 * j) * 128 + n];
        const float a1 = W[(size_t)(k0 + 2 * j + 1) * 128 + n];
        split_pack(a0, a1, hu[j], lu[j]);
    }
    whi[(kt * 8 + nt) * 64 + lane] = make_uint4(hu[0], hu[1], hu[2], hu[3]);
    wlo[(kt * 8 + nt) * 64 + lane] = make_uint4(lu[0], lu[1], lu[2], lu[3]);
}

// ---------------------------------------------------------------------------
// K1: h = x @ W via bf16x3 MFMA. 64 rows x 128 cols per 256-thr block.
// Wave w: col tiles {2w, 2w+1}. LDS-staged epilogue: coalesced bf16 h store +
// per-(row,head) a_src/a_dst dots (no shuffles, fp32-exact).
// ---------------------------------------------------------------------------
__global__ __launch_bounds__(256, 3) void gemm_mfma_kernel(
    const float* __restrict__ x, const uint4* __restrict__ whi,
    const uint4* __restrict__ wlo, const float* __restrict__ att_src,
    const float* __restrict__ att_dst, unsigned short* __restrict__ h_bf,
    float* __restrict__ a_src, float* __restrict__ a_dst)
{
    __shared__ float st[64][132];

    const int tid  = threadIdx.x;
    const int wave = tid >> 6;
    const int lane = tid & 63;
    const int c    = lane & 15;
    const int quad = lane >> 4;
    const int row0 = blockIdx.x * 64;

    floatx4 acc[4][2];
#pragma unroll
    for (int i = 0; i < 4; ++i)
#pragma unroll
        for (int j = 0; j < 2; ++j) acc[i][j] = (floatx4){0.f, 0.f, 0.f, 0.f};

    for (int kt = 0; kt < 4; ++kt) {
        short8 ahi[4], alo[4];
#pragma unroll
        for (int rt = 0; rt < 4; ++rt) {
            int r = row0 + rt * 16 + c;
            if (r >= N_NODES) r = N_NODES - 1;
            const float4* xp = (const float4*)&x[(size_t)r * 128 + kt * 32 + quad * 8];
            const float4 v0 = xp[0];
            const float4 v1 = xp[1];
            const float xv[8] = {v0.x, v0.y, v0.z, v0.w, v1.x, v1.y, v1.z, v1.w};
            union { short8 v; unsigned int u[4]; } H, L;
#pragma unroll
            for (int j = 0; j < 4; ++j)
                split_pack(xv[2 * j], xv[2 * j + 1], H.u[j], L.u[j]);
            ahi[rt] = H.v;
            alo[rt] = L.v;
        }
#pragma unroll
        for (int ntl = 0; ntl < 2; ++ntl) {
            const int nti = wave * 2 + ntl;
            union { uint4 q; short8 v; } BH, BL;
            BH.q = whi[(kt * 8 + nti) * 64 + lane];
            BL.q = wlo[(kt * 8 + nti) * 64 + lane];
#pragma unroll
            for (int rt = 0; rt < 4; ++rt) {
                acc[rt][ntl] = __builtin_amdgcn_mfma_f32_16x16x32_bf16(
                    ahi[rt], BH.v, acc[rt][ntl], 0, 0, 0);
                acc[rt][ntl] = __builtin_amdgcn_mfma_f32_16x16x32_bf16(
                    alo[rt], BH.v, acc[rt][ntl], 0, 0, 0);
                acc[rt][ntl] = __builtin_amdgcn_mfma_f32_16x16x32_bf16(
                    ahi[rt], BL.v, acc[rt][ntl], 0, 0, 0);
            }
        }
    }

    // stage fp32 tile: C/D layout col=lane&15, row=quad*4+reg (m89-verified)
#pragma unroll
    for (int rt = 0; rt < 4; ++rt)
#pragma unroll
        for (int ntl = 0; ntl < 2; ++ntl)
#pragma unroll
            for (int reg = 0; reg < 4; ++reg)
                st[rt * 16 + quad * 4 + reg][(wave * 2 + ntl) * 16 + c] =
                    acc[rt][ntl][reg];
    __syncthreads();

    // coalesced bf16 h store: thread t -> row t>>2, 32-ch segment (t&3)*32
    {
        const int hr = tid >> 2;
        const int hs = (tid & 3) * 32;
        const int grow = row0 + hr;
        if (grow < N_NODES) {
            uint4* dp = (uint4*)&h_bf[(size_t)grow * 128 + hs];
#pragma unroll
            for (int g = 0; g < 4; ++g) {
                uint4 pk;
                pk.x = pack_bf2(st[hr][hs + g * 8 + 0], st[hr][hs + g * 8 + 1]);
                pk.y = pack_bf2(st[hr][hs + g * 8 + 2], st[hr][hs + g * 8 + 3]);
                pk.z = pack_bf2(st[hr][hs + g * 8 + 4], st[hr][hs + g * 8 + 5]);
                pk.w = pack_bf2(st[hr][hs + g * 8 + 6], st[hr][hs + g * 8 + 7]);
                dp[g] = pk;
            }
        }
    }
    // a-terms: thread t -> (row t&63, head t>>6), full 32-ch dot, fp32-exact
    {
        const int ar = tid & 63;
        const int ah = tid >> 6;
        float ps = 0.f, pd = 0.f;
#pragma unroll 8
        for (int i = 0; i < 32; ++i) {
            const float hv = st[ar][ah * 32 + i];
            ps = fmaf(hv, att_src[ah * 32 + i], ps);
            pd = fmaf(hv, att_dst[ah * 32 + i], pd);
        }
        const int gr2 = row0 + ar;
        if (gr2 < N_NODES) {
            a_src[gr2 * 4 + ah] = ps;
            a_dst[gr2 * 4 + ah] = pd;
        }
    }
}

// ---------------------------------------------------------------------------
// K2: bucket histogram, LDS-privatized. 512 blocks x 3125 edges.
// ---------------------------------------------------------------------------
#define BH_EPB 3125
__global__ __launch_bounds__(256) void bucket_hist_kernel(
    const int* __restrict__ dst, int* __restrict__ bcnt)
{
    __shared__ int cnt[NB_BUCKET];
    const int tid = threadIdx.x;
    for (int i = tid; i < NB_BUCKET; i += 256) cnt[i] = 0;
    __syncthreads();
    const int e0 = blockIdx.x * BH_EPB;
    for (int i = tid; i < BH_EPB; i += 256)
        atomicAdd(&cnt[dst[e0 + i] >> 7], 1);
    __syncthreads();
    for (int i = tid; i < NB_BUCKET; i += 256)
        if (cnt[i]) atomicAdd(&bcnt[i], cnt[i]);
}

// ---------------------------------------------------------------------------
// K3: scan 782 bucket counts. One block, 1024 threads.
// ---------------------------------------------------------------------------
__global__ __launch_bounds__(1024) void bucket_scan_kernel(
    const int* __restrict__ bcnt, int* __restrict__ boff, int* __restrict__ bcur)
{
    const int tid  = threadIdx.x;
    const int lane = tid & 63;
    const int wv   = tid >> 6;
    const int v    = (tid < NB_BUCKET) ? bcnt[tid] : 0;

    int sv = v;
#pragma unroll
    for (int off = 1; off < 64; off <<= 1) {
        int u = __shfl_up(sv, off);
        if (lane >= off) sv += u;
    }
    __shared__ int wsum[16];
    if (lane == 63) wsum[wv] = sv;
    __syncthreads();
    if (tid == 0) {
        int run = 0;
#pragma unroll
        for (int k = 0; k < 16; ++k) { int t = wsum[k]; wsum[k] = run; run += t; }
    }
    __syncthreads();
    if (tid < NB_BUCKET) {
        const int excl = wsum[wv] + sv - v;
        boff[tid] = excl;
        bcur[tid] = excl;
    }
    if (tid == 0) boff[NB_BUCKET] = N_EDGES;
}

// ---------------------------------------------------------------------------
// K4: bucketed scatter with per-block chunk claiming. 512 blocks x 3125 edges.
// tmp entry = (src << 7) | (dst & 127)
// ---------------------------------------------------------------------------
#define S1_EPB 3125
__global__ __launch_bounds__(256) void scat1_kernel(
    const int* __restrict__ src, const int* __restrict__ dst,
    int* __restrict__ bcur, unsigned int* __restrict__ tmp)
{
    __shared__ int cnt[NB_BUCKET];
    const int tid = threadIdx.x;
    for (int i = tid; i < NB_BUCKET; i += 256) cnt[i] = 0;
    __syncthreads();
    const int e0 = blockIdx.x * S1_EPB;
    for (int i = tid; i < S1_EPB; i += 256)
        atomicAdd(&cnt[dst[e0 + i] >> 7], 1);
    __syncthreads();
    for (int b = tid; b < NB_BUCKET; b += 256) {
        const int c = cnt[b];
        cnt[b] = c ? atomicAdd(&bcur[b], c) : 0;
    }
    __syncthreads();
    for (int i = tid; i < S1_EPB; i += 256) {
        const int d = dst[e0 + i];
        const int s = src[e0 + i];
        const int p = atomicAdd(&cnt[d >> 7], 1);
        tmp[p] = ((unsigned int)s << 7) | (unsigned int)(d & 127);
    }
}

// ---------------------------------------------------------------------------
// K5: fused per-bucket softmax-aggregate-ELU. One block per bucket.
// LDS fp32 accumulator [128 nodes][128 ch]; waves stream bucket edges
// independently (no barrier in the loop); LDS float atomics accumulate.
// ---------------------------------------------------------------------------
#define AGG_PAD 132
__global__ __launch_bounds__(256, 2) void agg_bucket_kernel(
    const unsigned int* __restrict__ tmp, const int* __restrict__ boff,
    const unsigned int* __restrict__ h32,
    const float* __restrict__ a_src, const float* __restrict__ a_dst,
    const float* __restrict__ bias, float* __restrict__ out)
{
    __shared__ float acc[128][AGG_PAD];   // 67.6 KB
    __shared__ float den[128][4];         // 2 KB
    __shared__ float stg[4][4][64][2];    // [wave][head][j][{ubits, ex}] 8 KB

    const int tid  = threadIdx.x;
    const int wv   = tid >> 6;
    const int lane = tid & 63;
    const int b    = blockIdx.x;
    const int base = boff[b];
    const int end  = boff[b + 1];
    const int node0 = b << 7;

    // zero accumulators
    {
        float4 z = make_float4(0.f, 0.f, 0.f, 0.f);
        float4* az = (float4*)&acc[0][0];
        for (int i = tid; i < 128 * AGG_PAD / 4; i += 256) az[i] = z;
        float4* dz = (float4*)&den[0][0];
        if (tid < 128) dz[tid] = z;
    }
    __syncthreads();

    const int hq = lane >> 4;
    const unsigned int ch2 = 2 * (unsigned int)lane;

    for (int j0 = base + wv * 64; j0 < end; j0 += 256) {
        const int n = min(64, end - j0);

        float uf = __uint_as_float(0u);
        float e0 = 0.f, e1 = 0.f, e2 = 0.f, e3 = 0.f;
        if (lane < n) {
            const unsigned int u = tmp[j0 + lane];
            const int s = (int)(u >> 7);
            const int d = (int)(u & 127u);
            uf = __uint_as_float(u);
            const float4 as4 = ((const float4*)a_src)[s];
            const float4 ad4 = ((const float4*)a_dst)[node0 + d];
            e0 = __expf(leaky(as4.x + ad4.x));
            e1 = __expf(leaky(as4.y + ad4.y));
            e2 = __expf(leaky(as4.z + ad4.z));
            e3 = __expf(leaky(as4.w + ad4.w));
            atomicAdd(&den[d][0], e0);
            atomicAdd(&den[d][1], e1);
            atomicAdd(&den[d][2], e2);
            atomicAdd(&den[d][3], e3);
        }
        *(float2*)&stg[wv][0][lane][0] = make_float2(uf, e0);
        *(float2*)&stg[wv][1][lane][0] = make_float2(uf, e1);
        *(float2*)&stg[wv][2][lane][0] = make_float2(uf, e2);
        *(float2*)&stg[wv][3][lane][0] = make_float2(uf, e3);
        // per-wave private staging: no __syncthreads needed

        const int cnt = (n + 3) & ~3;   // zero-ex pad entries are harmless
        const float2* sp = (const float2*)&stg[wv][hq][0][0];
        for (int j = 0; j < cnt; j += 4) {
            const float2 f0 = sp[j + 0];
            const float2 f1 = sp[j + 1];
            const float2 f2 = sp[j + 2];
            const float2 f3 = sp[j + 3];
            const unsigned int u0 = __float_as_uint(f0.x);
            const unsigned int u1 = __float_as_uint(f1.x);
            const unsigned int u2 = __float_as_uint(f2.x);
            const unsigned int u3 = __float_as_uint(f3.x);
            const unsigned int hw0 = h32[((u0 >> 7) << 6) + lane];
            const unsigned int hw1 = h32[((u1 >> 7) << 6) + lane];
            const unsigned int hw2 = h32[((u2 >> 7) << 6) + lane];
            const unsigned int hw3 = h32[((u3 >> 7) << 6) + lane];
            const int d0 = (int)(u0 & 127u);
            const int d1 = (int)(u1 & 127u);
            const int d2 = (int)(u2 & 127u);
            const int d3 = (int)(u3 & 127u);
            atomicAdd(&acc[d0][ch2 + 0], bf_lo(hw0) * f0.y);
            atomicAdd(&acc[d0][ch2 + 1], bf_hi(hw0) * f0.y);
            atomicAdd(&acc[d1][ch2 + 0], bf_lo(hw1) * f1.y);
            atomicAdd(&acc[d1][ch2 + 1], bf_hi(hw1) * f1.y);
            atomicAdd(&acc[d2][ch2 + 0], bf_lo(hw2) * f2.y);
            atomicAdd(&acc[d2][ch2 + 1], bf_hi(hw2) * f2.y);
            atomicAdd(&acc[d3][ch2 + 0], bf_lo(hw3) * f3.y);
            atomicAdd(&acc[d3][ch2 + 1], bf_hi(hw3) * f3.y);
        }
    }
    __syncthreads();

    // epilogue: thread t -> node t>>1, 64-ch half (t&1)*64
    {
        const int nd = tid >> 1;
        const int c0 = (tid & 1) * 64;
        const int node = node0 + nd;
        if (node < N_NODES) {
            const float4 dn = *(const float4*)&den[nd][0];
            float inv[4];
            inv[0] = 1.0f / (dn.x + 1e-16f);
            inv[1] = 1.0f / (dn.y + 1e-16f);
            inv[2] = 1.0f / (dn.z + 1e-16f);
            inv[3] = 1.0f / (dn.w + 1e-16f);
#pragma unroll
            for (int g = 0; g < 16; ++g) {
                const int ch = c0 + g * 4;
                const float4 v  = *(const float4*)&acc[nd][ch];
                const float4 bs = *(const float4*)&bias[ch];
                const float iv = inv[ch >> 5];
                float o0 = v.x * iv + bs.x;
                float o1 = v.y * iv + bs.y;
                float o2 = v.z * iv + bs.z;
                float o3 = v.w * iv + bs.w;
                o0 = o0 > 0.f ? o0 : expm1f(o0);
                o1 = o1 > 0.f ? o1 : expm1f(o1);
                o2 = o2 > 0.f ? o2 : expm1f(o2);
                o3 = o3 > 0.f ? o3 : expm1f(o3);
                *(float4*)&out[(size_t)node * 128 + ch] =
                    make_float4(o0, o1, o2, o3);
            }
        }
    }
}

// ---------------------------------------------------------------------------
extern "C" void kernel_launch(void* const* d_in, const int* in_sizes, int n_in,
                              void* d_out, int out_size, void* d_ws, size_t ws_size,
                              hipStream_t stream)
{
    const float* x       = (const float*)d_in[0];
    const int*   ei      = (const int*)  d_in[1];
    const float* W       = (const float*)d_in[2];
    const float* att_src = (const float*)d_in[3];
    const float* att_dst = (const float*)d_in[4];
    const float* bias    = (const float*)d_in[5];
    float*       out     = (float*)d_out;

    char* ws = (char*)d_ws;
    unsigned short* h_bf = (unsigned short*)(ws + OFF_H);
    unsigned int*   h32  = (unsigned int*)(ws + OFF_H);
    float* a_src = (float*)(ws + OFF_ASRC);
    float* a_dst = (float*)(ws + OFF_ADST);
    int*   bcnt  = (int*)  (ws + OFF_BCNT);
    int*   boff  = (int*)  (ws + OFF_BOFF);
    int*   bcur  = (int*)  (ws + OFF_BCUR);
    uint4* whi   = (uint4*)(ws + OFF_WHI);
    uint4* wlo   = (uint4*)(ws + OFF_WLO);
    unsigned int* tmp = (unsigned int*)(ws + OFF_TMP);

    const int* srcp = ei;
    const int* dstp = ei + N_EDGES;

    hipMemsetAsync(bcnt, 0, NB_BUCKET * sizeof(int), stream);

    wfrag_kernel<<<8, 256, 0, stream>>>(W, whi, wlo);
    gemm_mfma_kernel<<<(N_NODES + 63) / 64, 256, 0, stream>>>(
        x, whi, wlo, att_src, att_dst, h_bf, a_src, a_dst);

    bucket_hist_kernel<<<N_EDGES / BH_EPB, 256, 0, stream>>>(dstp, bcnt);
    bucket_scan_kernel<<<1, 1024, 0, stream>>>(bcnt, boff, bcur);
    scat1_kernel<<<N_EDGES / S1_EPB, 256, 0, stream>>>(srcp, dstp, bcur, tmp);

    agg_bucket_kernel<<<NB_BUCKET, 256, 0, stream>>>(
        tmp, boff, h32, a_src, a_dst, bias, out);
}